// Round 8
// baseline (247.549 us; speedup 1.0000x reference)
//
#include <hip/hip_runtime.h>

#define NTIME   256
#define NBATCH  8192
#define NHIST   6
#define NSIZE   8
#define K       4          // independent chains (batch elements) per thread
#define CSTRIDE 2048       // NBATCH / K

// One thread integrates K=4 independent batch chains, interleaved at the
// instruction level: each chain's ~450cy of dependency-stall (we were
// latency-bound at 1 chain/thread) is filled by the other chains' work.
// Per chain, the backward-Euler step is the scalar Newton solve in
// x = over_next (rounds 2-7):
//   F(x) = x - s+(x)*(1-d+(x)) + sum_i hi+(x) = 0
//   s+ = cs - E*dtfr;  hi+ = fma(Ci,dtfr,hi)*rc_i;  rc_i ~ 1-u+u^2 (Neumann)
//   d+ = dy + d_coef*dtabsfr      (dt folded; dt*er == delta_e exactly)
// ONE eval/step from quadratic warm start + first-order Taylor shift of the
// accepted state to x-dx (validated: 8/2/1-eval rounds all absmax 2.0).
// Inputs: 3-slot ring per chain; body t loads step t+2 into the slot freed
// last body (2 bodies x ~560 busy cy covers HBM).

__device__ __forceinline__ float frcp(float x) { return __builtin_amdgcn_rcpf(x); }

__global__ __launch_bounds__(64) void integrate_kernel(
    const float* __restrict__ times,
    const float* __restrict__ strains,
    const float* __restrict__ temps,
    const float* __restrict__ pE,
    const float* __restrict__ pn,
    const float* __restrict__ peta,
    const float* __restrict__ ps0,
    const float* __restrict__ Cp,
    const float* __restrict__ gp_,
    const float* __restrict__ pd_coef,
    float* __restrict__ out)
{
    const int lane = blockIdx.x * 64 + threadIdx.x;   // 0..2047

    const float E      = pE[0];
    const float n      = pn[0];
    const float eta    = peta[0];
    const float s0     = ps0[0];
    const float d_coef = pd_coef[0];
    float Cl[NHIST], gl[NHIST];
#pragma unroll
    for (int i = 0; i < NHIST; ++i) { Cl[i] = Cp[i]; gl[i] = gp_[i]; }
    const float A0 = ((Cl[0] + Cl[1]) + (Cl[2] + Cl[3])) + (Cl[4] + Cl[5]);

    const float inv_s0  = 1.0f / s0;
    const float inv_eta = 1.0f / eta;
    const bool  n5   = (n == 5.0f);              // wave-uniform
    const float i2   = inv_s0 * inv_s0;
    const float i5   = i2 * i2 * inv_s0;
    const float nm1  = n - 1.0f;
    const float gsc0 = n * inv_s0;

    // per-chain state (all statically indexed after full unroll)
    float sy[K], dy[K], omdy[K], h0[K][NHIST];
    float xs[K], xsp[K], xspp[K];
    float tpv[K], epv[K];
    float sT[K][3], sE_[K][3], sTe[K][3];
    float4* optr[K];

#pragma unroll
    for (int c = 0; c < K; ++c) {
        const int b = lane + c * CSTRIDE;
        sy[c] = 0.f; dy[c] = 0.f; omdy[c] = 1.f;
#pragma unroll
        for (int i = 0; i < NHIST; ++i) h0[c][i] = 0.f;
        xs[c] = xsp[c] = xspp[c] = 0.f;
        tpv[c] = times[b]; epv[c] = strains[b];
        // trajectory row 0 = zeros
        float4 z4 = make_float4(0.f, 0.f, 0.f, 0.f);
        float4* op = (float4*)(out + (size_t)b * NSIZE);
        op[0] = z4; op[1] = z4;
        // preload steps 1,2 into slots 1,2 (slot = t%3); body t=1 loads step 3
        const size_t o1 = (size_t)NBATCH + b;
        sT[c][1] = times[o1]; sE_[c][1] = strains[o1]; sTe[c][1] = temps[o1];
        const size_t o2 = (size_t)2 * NBATCH + b;
        sT[c][2] = times[o2]; sE_[c][2] = strains[o2]; sTe[c][2] = temps[o2];
        optr[c] = (float4*)(out + ((size_t)NBATCH + b) * NSIZE);
    }

    // one chain, one step, consuming slot S (compile-time constants c, S)
#define STEP(c, S)                                                             \
    {                                                                          \
        const float dtn_ = sT[c][S] - tpv[c];                                  \
        const float Ee_  = E * (sE_[c][S] - epv[c]);                           \
        const float sc_  = inv_eta * __expf(-sTe[c][S] * 0.001f);              \
        const float dts5c_ = (i5 * dtn_) * sc_;                                \
        const float dtg5c_ = n * dts5c_;                                       \
        tpv[c] = sT[c][S]; epv[c] = sE_[c][S];                                 \
        const float cs_ = Ee_ + sy[c];                                         \
        float x = fmaf(3.0f, xs[c] - xsp[c], xspp[c]);                         \
        const float sg_ = (x >= 0.0f) ? 1.0f : -1.0f;                          \
        const float ax_ = fabsf(x);                                            \
        float dtabsfr_, dtgp_;                                                 \
        if (n5) {                                                              \
            const float p_ = ax_ * ax_;                                        \
            const float q_ = p_ * p_;                                          \
            dtabsfr_ = (q_ * ax_) * dts5c_;                                    \
            dtgp_    = q_ * dtg5c_;                                            \
        } else {                                                               \
            const float a_   = ax_ * inv_s0;                                   \
            const float pm1_ = __powf(a_, nm1);                                \
            dtabsfr_ = dtn_ * (pm1_ * (a_ * sc_));                             \
            dtgp_    = dtn_ * ((gsc0 * sc_) * pm1_);                           \
        }                                                                      \
        const float dtfr_ = sg_ * dtabsfr_;                                    \
        const float sn_   = fmaf(-E, dtfr_, cs_);                              \
        const float dn_   = fmaf(d_coef, dtabsfr_, dy[c]);                     \
        const float omd_  = fmaf(-d_coef, dtabsfr_, omdy[c]);                  \
        const float B0_ = ((gl[0] * h0[c][0] + gl[1] * h0[c][1])               \
                         + (gl[2] * h0[c][2] + gl[3] * h0[c][3]))              \
                         + (gl[4] * h0[c][4] + gl[5] * h0[c][5]);              \
        float hn_[NHIST];                                                      \
        _Pragma("unroll")                                                      \
        for (int i_ = 0; i_ < NHIST; ++i_) {                                   \
            const float u_  = gl[i_] * dtabsfr_;                               \
            const float rc_ = fmaf(u_, u_, 1.0f) - u_;                         \
            hn_[i_] = fmaf(Cl[i_], dtfr_, h0[c][i_]) * rc_;                    \
        }                                                                      \
        const float sumh_ = ((hn_[0] + hn_[1]) + (hn_[2] + hn_[3]))            \
                          + (hn_[4] + hn_[5]);                                 \
        const float F_  = fmaf(-sn_, omd_, x) + sumh_;                         \
        const float Fp_ = fmaf(dtgp_, fmaf(E, omd_, fmaf(-sg_, B0_, A0)),      \
                               1.0f);                                          \
        const float dx_  = F_ * frcp(Fp_);                                     \
        const float cdx_ = dtgp_ * dx_;                                        \
        x -= dx_;                                                              \
        sy[c] = fmaf(E, cdx_, sn_);                                            \
        dy[c] = dn_; omdy[c] = omd_;                                           \
        _Pragma("unroll")                                                      \
        for (int i_ = 0; i_ < NHIST; ++i_)                                     \
            h0[c][i_] = fmaf(-Cl[i_], cdx_, hn_[i_]);                          \
        optr[c][0] = make_float4(sy[c], h0[c][0], h0[c][1], h0[c][2]);         \
        optr[c][1] = make_float4(h0[c][3], h0[c][4], h0[c][5], dn_);           \
        optr[c] += NBATCH * 2;   /* row stride: NBATCH*NSIZE floats */         \
        xspp[c] = xsp[c]; xsp[c] = xs[c]; xs[c] = x;                           \
    }

    // body t: load step t+2 into slot (t+2)%3 (freed last body), consume slot t%3
#define BODY(SC, SL, tt)                                                       \
    _Pragma("unroll")                                                          \
    for (int c_ = 0; c_ < K; ++c_) {                                           \
        const int tq_ = ((tt) + 2 < NTIME) ? (tt) + 2 : (NTIME - 1);           \
        const size_t o_ = (size_t)tq_ * NBATCH + (lane + c_ * CSTRIDE);        \
        sT[c_][SL] = times[o_]; sE_[c_][SL] = strains[o_];                     \
        sTe[c_][SL] = temps[o_];                                               \
    }                                                                          \
    _Pragma("unroll")                                                          \
    for (int c_ = 0; c_ < K; ++c_) STEP(c_, SC)

    // 255 steps = 85 * 3, exact; slot index = t % 3
    for (int t = 1; t <= 253; t += 3) {
        BODY(1, 0, t);         // consume slot1, load t+2 -> slot0
        BODY(2, 1, t + 1);     // consume slot2, load t+3 -> slot1
        BODY(0, 2, t + 2);     // consume slot0, load t+4 -> slot2
    }
#undef BODY
#undef STEP
}

extern "C" void kernel_launch(void* const* d_in, const int* in_sizes, int n_in,
                              void* d_out, int out_size, void* d_ws, size_t ws_size,
                              hipStream_t stream) {
    const float* times   = (const float*)d_in[0];
    const float* strains = (const float*)d_in[1];
    const float* temps   = (const float*)d_in[2];
    const float* E       = (const float*)d_in[3];
    const float* n       = (const float*)d_in[4];
    const float* eta     = (const float*)d_in[5];
    const float* s0      = (const float*)d_in[6];
    const float* C       = (const float*)d_in[7];
    const float* g       = (const float*)d_in[8];
    const float* d_coef  = (const float*)d_in[9];
    float* out = (float*)d_out;

    dim3 grid(NBATCH / (64 * K)), block(64);
    hipLaunchKernelGGL(integrate_kernel, grid, block, 0, stream,
                       times, strains, temps, E, n, eta, s0, C, g, d_coef, out);
}

// Round 9
// 47.904 us; speedup vs baseline: 5.1676x; 5.1676x over previous
//
#include <hip/hip_runtime.h>

#define NTIME  256
#define NBATCH 8192
#define NHIST  6
#define NSIZE  8

// One thread per batch element (128 waves; wall time = 255 x per-step serial
// latency, so the ONLY lever is shortening the step's dependent chain).
// Backward-Euler step as scalar Newton in x = over_next:
//   F(x) = x - s+(x)*(1-d+(x)) + sum_i hi+(x) = 0
//   s+ = cs - E*dtfr;  hi+ = fma(Ci,dtfr_eff,hi)*(1-u_i);  u_i = gi*|dtfr|
//   d+ = dy + d_coef*|dtfr|       (dt folded; dt*er == delta_e exactly)
// ONE eval/step from quadratic warm start; first-order Taylor shift of the
// accepted state to x-dx is merged into the NEXT step's drive
// (dtfr_eff = dtfr - cdx_prev), exact algebra vs round 6/7. F' drops the
// Sum(g h) term (perturbs Newton direction ~2%, fixed point unchanged).
// Template<N5> removes the uniform power-law branch from the loop body;
// __launch_bounds__(64,1) frees the register budget so the scheduler can
// hide VALU/trans latency. 6-deep input load pipeline as before.

__device__ __forceinline__ float frcp(float x) { return __builtin_amdgcn_rcpf(x); }

template<bool N5>
__device__ void integrate(
    const float* __restrict__ times,
    const float* __restrict__ strains,
    const float* __restrict__ temps,
    float* __restrict__ out,
    const int b,
    const float E, const float n, const float eta, const float s0,
    const float d_coef,
    const float* __restrict__ Cp,
    const float* __restrict__ gp_)
{
    float Cl[NHIST], gl[NHIST];
#pragma unroll
    for (int i = 0; i < NHIST; ++i) { Cl[i] = Cp[i]; gl[i] = gp_[i]; }
    const float A0 = ((Cl[0] + Cl[1]) + (Cl[2] + Cl[3])) + (Cl[4] + Cl[5]);

    const float inv_s0  = 1.0f / s0;
    const float inv_eta = 1.0f / eta;
    const float i2   = inv_s0 * inv_s0;
    const float i5   = i2 * i2 * inv_s0;
    const float nm1  = n - 1.0f;
    const float gsc0 = n * inv_s0;

    // loop-carried state
    float sy = 0.f, dy = 0.f, omdy = 1.f, cdxp = 0.f;
    float h0[NHIST];
#pragma unroll
    for (int i = 0; i < NHIST; ++i) h0[i] = 0.f;
    float xs = 0.f, xsp = 0.f, xspp = 0.f;

    // trajectory row 0 = zeros
    {
        float4 z4 = make_float4(0.f, 0.f, 0.f, 0.f);
        float4* op = (float4*)(out + (size_t)b * NSIZE);
        op[0] = z4; op[1] = z4;
    }

    // ---- prologue: step-0/1 data + preload slots for steps 2..7
    const float tA = times[b],                  eA = strains[b];
    const float tB = times[(size_t)NBATCH + b], eB = strains[(size_t)NBATCH + b];
    const float TB = temps[(size_t)NBATCH + b];

    float sT0, sE0, sTe0, sT1, sE1, sTe1, sT2, sE2, sTe2,
          sT3, sE3, sTe3, sT4, sE4, sTe4, sT5, sE5, sTe5;
#define PRELOAD(SL, STEP)                                                      \
    { const size_t o_ = (size_t)(STEP) * NBATCH + b;                           \
      sT##SL = times[o_]; sE##SL = strains[o_]; sTe##SL = temps[o_]; }
    PRELOAD(2, 2) PRELOAD(3, 3) PRELOAD(4, 4)
    PRELOAD(5, 5) PRELOAD(0, 6) PRELOAD(1, 7)
#undef PRELOAD

    // per-step constants, 2 sets keyed by step parity
    float dt_0 = 0.f, sc_0 = 0.f, dts5c_0 = 0.f, dtg5c_0 = 0.f, Ee_0 = 0.f;
    float dt_1 = 0.f, sc_1 = 0.f, dts5c_1 = 0.f, dtg5c_1 = 0.f, Ee_1 = 0.f;
    {   // constants for step 1 (parity 1)
        dt_1    = tB - tA;
        Ee_1    = E * (eB - eA);
        sc_1    = inv_eta * __expf(-TB * 0.001f);
        dts5c_1 = (i5 * dt_1) * sc_1;
        dtg5c_1 = n * dts5c_1;
    }
    float tcur = tB, ecur = eB;

    float4* op4 = (float4*)(out + ((size_t)NBATCH + b) * NSIZE);

#define LOADSLOT(SL, tt)                                                       \
    {                                                                          \
        const int tq_ = ((tt) < NTIME) ? (tt) : (NTIME - 1);                   \
        const size_t o_ = (size_t)tq_ * NBATCH + b;                            \
        sT##SL = times[o_]; sE##SL = strains[o_]; sTe##SL = temps[o_];         \
    }

#define PREP(SL, PAR)                                                          \
    {                                                                          \
        const float dtn_ = sT##SL - tcur;                                      \
        Ee_##PAR = E * (sE##SL - ecur);                                        \
        const float scx_ = inv_eta * __expf(-sTe##SL * 0.001f);                \
        dts5c_##PAR = (i5 * dtn_) * scx_;                                      \
        dtg5c_##PAR = n * dts5c_##PAR;                                         \
        if constexpr (!N5) { dt_##PAR = dtn_; sc_##PAR = scx_; }               \
        tcur = sT##SL; ecur = sE##SL;                                          \
    }

    // ---- step head: through frcp(F') so trans latency hides under the tail
#define CORE_HEAD(PAR)                                                         \
        const float cs_ = Ee_##PAR + sy;                                       \
        float x = fmaf(3.0f, xs - xsp, xspp);                                  \
        float dtfr_, dtgp_;                                                    \
        if constexpr (N5) {                                                    \
            const float p_ = x * x;                                            \
            const float q_ = p_ * p_;                                          \
            dtfr_ = (q_ * x) * dts5c_##PAR;                                    \
            dtgp_ = q_ * dtg5c_##PAR;                                          \
        } else {                                                               \
            const float sg_ = (x >= 0.0f) ? 1.0f : -1.0f;                      \
            const float ax_ = fabsf(x);                                        \
            const float a_  = ax_ * inv_s0;                                    \
            const float pm1_ = __powf(a_, nm1);                                \
            dtfr_ = sg_ * (dt_##PAR * (pm1_ * (a_ * sc_##PAR)));               \
            dtgp_ = dt_##PAR * ((gsc0 * sc_##PAR) * pm1_);                     \
        }                                                                      \
        const float adtfr_ = fabsf(dtfr_);                                     \
        const float dtfe_  = dtfr_ - cdxp;      /* Taylor-merged drive */      \
        const float sn_  = fmaf(-E, dtfr_, cs_);                               \
        const float dn_  = fmaf(d_coef, adtfr_, dy);                           \
        const float omd_ = fmaf(-d_coef, adtfr_, omdy);                        \
        const float Fp_  = fmaf(dtgp_, fmaf(E, omd_, A0), 1.0f);               \
        const float rFp_ = frcp(Fp_);

#define CORE_TAIL()                                                            \
        _Pragma("unroll")                                                      \
        for (int i_ = 0; i_ < NHIST; ++i_) {                                   \
            const float u_ = gl[i_] * adtfr_;                                  \
            h0[i_] = fmaf(Cl[i_], dtfe_, h0[i_]) * (1.0f - u_);                \
        }                                                                      \
        const float sumh_ = ((h0[0] + h0[1]) + (h0[2] + h0[3]))                \
                          + (h0[4] + h0[5]);                                   \
        const float F_   = fmaf(-sn_, omd_, x) + sumh_;                        \
        const float dx_  = F_ * rFp_;                                          \
        const float cdx_ = dtgp_ * dx_;                                        \
        xspp = xsp; xsp = xs; xs = x - dx_;                                    \
        cdxp = cdx_;                                                           \
        sy = fmaf(E, cdx_, sn_);                                               \
        dy = dn_; omdy = omd_;                                                 \
        const float c0_ = fmaf(-Cl[0], cdx_, h0[0]);                           \
        const float c1_ = fmaf(-Cl[1], cdx_, h0[1]);                           \
        const float c2_ = fmaf(-Cl[2], cdx_, h0[2]);                           \
        const float c3_ = fmaf(-Cl[3], cdx_, h0[3]);                           \
        const float c4_ = fmaf(-Cl[4], cdx_, h0[4]);                           \
        const float c5_ = fmaf(-Cl[5], cdx_, h0[5]);                           \
        op4[0] = make_float4(sy, c0_, c1_, c2_);                               \
        op4[1] = make_float4(c3_, c4_, c5_, dn_);                              \
        op4 += NBATCH * 2;

#define BODY(P, PN, PAR, NPAR, tt)                                             \
    {                                                                          \
        LOADSLOT(P, (tt) + 6);                                                 \
        CORE_HEAD(PAR)                                                         \
        PREP(PN, NPAR);    /* independent work under frcp/h-loop latency */    \
        CORE_TAIL()                                                            \
    }

    // main loop: 42 iterations x 6 bodies = steps 1..252
    for (int t = 1; t <= 247; t += 6) {
        BODY(1, 2, 1, 0, t);
        BODY(2, 3, 0, 1, t + 1);
        BODY(3, 4, 1, 0, t + 2);
        BODY(4, 5, 0, 1, t + 3);
        BODY(5, 0, 1, 0, t + 4);
        BODY(0, 1, 0, 1, t + 5);
    }
    // tail: steps 253 (par1), 254 (par0), 255 (par1)
    { CORE_HEAD(1) PREP(2, 0); CORE_TAIL() }
    { CORE_HEAD(0) PREP(3, 1); CORE_TAIL() }
    { CORE_HEAD(1) CORE_TAIL() }

#undef BODY
#undef CORE_TAIL
#undef CORE_HEAD
#undef PREP
#undef LOADSLOT
}

__global__ __launch_bounds__(64, 1) void integrate_kernel(
    const float* __restrict__ times,
    const float* __restrict__ strains,
    const float* __restrict__ temps,
    const float* __restrict__ pE,
    const float* __restrict__ pn,
    const float* __restrict__ peta,
    const float* __restrict__ ps0,
    const float* __restrict__ Cp,
    const float* __restrict__ gp_,
    const float* __restrict__ pd_coef,
    float* __restrict__ out)
{
    const int b = blockIdx.x * 64 + threadIdx.x;
    const float E = pE[0], n = pn[0], eta = peta[0], s0 = ps0[0];
    const float d_coef = pd_coef[0];
    if (n == 5.0f)
        integrate<true >(times, strains, temps, out, b, E, n, eta, s0, d_coef, Cp, gp_);
    else
        integrate<false>(times, strains, temps, out, b, E, n, eta, s0, d_coef, Cp, gp_);
}

extern "C" void kernel_launch(void* const* d_in, const int* in_sizes, int n_in,
                              void* d_out, int out_size, void* d_ws, size_t ws_size,
                              hipStream_t stream) {
    const float* times   = (const float*)d_in[0];
    const float* strains = (const float*)d_in[1];
    const float* temps   = (const float*)d_in[2];
    const float* E       = (const float*)d_in[3];
    const float* n       = (const float*)d_in[4];
    const float* eta     = (const float*)d_in[5];
    const float* s0      = (const float*)d_in[6];
    const float* C       = (const float*)d_in[7];
    const float* g       = (const float*)d_in[8];
    const float* d_coef  = (const float*)d_in[9];
    float* out = (float*)d_out;

    dim3 grid(NBATCH / 64), block(64);
    hipLaunchKernelGGL(integrate_kernel, grid, block, 0, stream,
                       times, strains, temps, E, n, eta, s0, C, g, d_coef, out);
}